// Round 7
// baseline (39403.290 us; speedup 1.0000x reference)
//
#include <hip/hip_runtime.h>
#include <math.h>

// ---------------- problem constants ----------------
#define BB 8
#define TT 512
#define LL 20
#define NBLK 64
#define NTHR 256

typedef float f4 __attribute__((ext_vector_type(4)));
typedef unsigned long long ull;

__constant__ int c_dil[LL] = {1,2,4,8,16,32,64,128,256,512,
                              1,2,4,8,16,32,64,128,256,512};
// ring float offsets, indexed by CONSUMING layer L (1..19); each ring has
// (d+2) slots of 1024 floats (slot = t mod (d+2); D-d>=2 steps of reuse slack)
__constant__ int c_roff2[LL] = {-1,0,4096,10240,20480,38912,73728,141312,274432,538624,
                                1064960,1068032,1072128,1078272,1088512,1106944,
                                1141760,1209344,1342464,1606656};

// ---------------- workspace layout (floats) ----------------
constexpr size_t OFF_RING = 0;          // 2,132,992 floats
constexpr size_t OFF_X    = 2132992;    // 4 slots * 768 f4 = 12,288 floats
constexpr size_t OFF_CHK  = 2145280;    // 64*20*512 f4 = 2,621,440 floats
constexpr size_t OFF_CB2  = 4766720;    // 20*256 folded z-bias
// end = 4,771,840 floats = 19.1 MB

// ---------------- LDS pool offsets (floats) ----------------
#define P_WSKIPC 0      // [2][128]
#define P_WFC    256    // [2][128]
#define P_WLOG   512    // [4][128]
#define P_WF0    1024   // [128]
#define P_WF1    1152
#define P_FB     1280
#define P_CONDZ  1408   // [20][4][8]
#define P_SFC    2048   // [2][8]
#define P_RESB   2064   // [20][2]
#define P_SKIPB  2104
#define P_LOGB   2144   // [4]
#define P_SKIPCB 2148   // [2]
#define P_XCUR   2152   // [8]
#define P_XPREV  2160
#define P_XNEW   2168
#define P_SZ     2176   // [32]
#define P_SL     2208   // [32]
#define P_SKACC  2240   // [16]
#define P_R2     2256   // [16]
#define P_WS     2272   // [19] ints (ring write-slot counters)
#define P_CF     2292   // [8][66]
#define P_PREVF  2820   // [2][8][132] ping-pong
#define P_HF     4932   // [2][8][132] ping-pong
#define P_RESF   7044   // [8][132]
#define P_RES0   8100   // [2][8][132]
#define P_CAND   10212  // [2][8][68] argmax candidates (val, idx)
#define POOL_FL  11300
// dynamic LDS request padded to 96KB so only 1 block fits per CU

// ---------------- coherent 16B exchange primitives ----------
__device__ __forceinline__ f4 ldx(const f4* p) {
    f4 r;
    asm volatile("global_load_dwordx4 %0, %1, off sc0 sc1\n\ts_waitcnt vmcnt(0)"
                 : "=v"(r) : "v"(p) : "memory");
    return r;
}
__device__ __forceinline__ void ldx2(const f4* p0, const f4* p1, f4& a, f4& b) {
    asm volatile("global_load_dwordx4 %0, %2, off sc0 sc1\n\t"
                 "global_load_dwordx4 %1, %3, off sc0 sc1\n\t"
                 "s_waitcnt vmcnt(0)"
                 : "=v"(a), "=v"(b) : "v"(p0), "v"(p1) : "memory");
}
__device__ __forceinline__ void ldx4v(const f4* p0, const f4* p1, const f4* p2, const f4* p3,
                                      f4& a, f4& b, f4& c, f4& d) {
    asm volatile("global_load_dwordx4 %0, %4, off sc0 sc1\n\t"
                 "global_load_dwordx4 %1, %5, off sc0 sc1\n\t"
                 "global_load_dwordx4 %2, %6, off sc0 sc1\n\t"
                 "global_load_dwordx4 %3, %7, off sc0 sc1\n\t"
                 "s_waitcnt vmcnt(0)"
                 : "=v"(a),"=v"(b),"=v"(c),"=v"(d)
                 : "v"(p0),"v"(p1),"v"(p2),"v"(p3) : "memory");
}
// NO vmcnt drain: the d+2 ring slotting removed the anti-dependence that
// r6's drained store guarded; draining serialized in-flight prefetches.
__device__ __forceinline__ void stx_nd(f4* p, f4 v) {
    asm volatile("global_store_dwordx4 %0, %1, off sc0 sc1"
                 :: "v"(p), "v"(v) : "memory");
}

__device__ __forceinline__ float dot4(f4 a, f4 b) {
    return a.x*b.x + a.y*b.y + a.z*b.z + a.w*b.w;
}

// payload element E in [0,16): r=E>>3, b=E&7; vec = [3 payload | tag]
__device__ __forceinline__ void publish16(f4* slot, int J, const float* sl, int e) {
    if (threadIdx.x < 6) {
        int q = threadIdx.x;
        f4 v;
        v.x = sl[3*q];
        v.y = (3*q+1 < 16) ? sl[3*q+1] : 0.f;
        v.z = (3*q+2 < 16) ? sl[3*q+2] : 0.f;
        v.w = __int_as_float(e);
        stx_nd(slot + J*6 + q, v);
    }
}
__device__ __forceinline__ void scat16(float* dst, f4 v, int vi, bool dorelu) {
    int j = vi / 6, q = vi - 6*j;
    #pragma unroll
    for (int i = 0; i < 3; ++i) {
        int E = 3*q + i;
        if (E < 16) {
            float x = v[i];
            if (dorelu) x = fmaxf(x, 0.f);
            dst[(E & 7)*132 + 2*j + (E >> 3)] = x;
        }
    }
}
__device__ __forceinline__ void consume16(const f4* slot, int e, float* dst, bool dorelu) {
    int m = threadIdx.x;
    const f4 *p0 = slot + m, *p1 = slot + 256 + m;
    f4 a, b;
    bool two = (m < 128);
    if (two) ldx2(p0, p1, a, b); else a = ldx(p0);
    while (__float_as_int(a.w) != e) { __builtin_amdgcn_s_sleep(1); a = ldx(p0); }
    if (two) { while (__float_as_int(b.w) != e) { __builtin_amdgcn_s_sleep(1); b = ldx(p1); } }
    scat16(dst, a, m, dorelu);
    if (two) scat16(dst, b, m + 256, dorelu);
}
// dual-consume: issue all lines for BOTH payloads, one waitcnt, then poll
__device__ __forceinline__ void consume_dual(const f4* sa, int ea, float* da,
                                             const f4* sb, int eb, float* db) {
    int m = threadIdx.x;
    const f4 *pa0 = sa + m, *pa1 = sa + 256 + m;
    const f4 *pb0 = sb + m, *pb1 = sb + 256 + m;
    f4 a0, a1, b0, b1;
    bool two = (m < 128);
    if (two) ldx4v(pa0, pa1, pb0, pb1, a0, a1, b0, b1);
    else     ldx2(pa0, pb0, a0, b0);
    while (__float_as_int(a0.w) != ea) { __builtin_amdgcn_s_sleep(1); a0 = ldx(pa0); }
    if (two) { while (__float_as_int(a1.w) != ea) { __builtin_amdgcn_s_sleep(1); a1 = ldx(pa1); } }
    while (__float_as_int(b0.w) != eb) { __builtin_amdgcn_s_sleep(1); b0 = ldx(pb0); }
    if (two) { while (__float_as_int(b1.w) != eb) { __builtin_amdgcn_s_sleep(1); b1 = ldx(pb1); } }
    scat16(da, a0, m, false);
    scat16(db, b0, m, false);
    if (two) { scat16(da, a1, m + 256, false); scat16(db, b1, m + 256, false); }
}
// argmax-candidate consume: scatter (val,idx) pairs to cand[r][b][jb]
__device__ __forceinline__ void consume16c(const f4* slot, int e, float* dst) {
    int m = threadIdx.x;
    const f4 *p0 = slot + m, *p1 = slot + 256 + m;
    f4 a, b;
    bool two = (m < 128);
    if (two) ldx2(p0, p1, a, b); else a = ldx(p0);
    while (__float_as_int(a.w) != e) { __builtin_amdgcn_s_sleep(1); a = ldx(p0); }
    if (two) { while (__float_as_int(b.w) != e) { __builtin_amdgcn_s_sleep(1); b = ldx(p1); } }
    #pragma unroll
    for (int s = 0; s < 2; ++s) {
        if (s == 1 && !two) break;
        f4 v = s ? b : a;
        int vi = m + s*256;
        int jb = vi / 6, q = vi - 6*jb;
        #pragma unroll
        for (int i = 0; i < 3; ++i) {
            int E = 3*q + i;
            if (E < 16) dst[(E >> 3)*544 + (E & 7)*68 + jb] = v[i];
        }
    }
}

// ============================================================
// prep: pack per-block per-layer weight chunks (SoA keyed by (role,g,k)),
// compute F_{l-1} = W1_l · Wres_{l-1} and fold zb into cb2.
// chunk (J,l): 512 f4. z part: [i*32 + g*8 + k], i<12 (W0 i<4, W1 4..7, F 8..11),
// cols j = 16k + 4*(i&3). dres part: [384 + u*32 + w*8 + k], row (r=w&1,skip=w>>1).
// ============================================================
__global__ void wn_pack(const float* __restrict__ causal_w,
                        const float* __restrict__ res_w,
                        const float* __restrict__ skip_w,
                        const float* __restrict__ causal_b,
                        const float* __restrict__ cond_b,
                        const float* __restrict__ res_b,
                        f4* __restrict__ chk, float* __restrict__ cb2)
{
    int bx = blockIdx.x;
    int J = bx / 20, l = bx - J*20;
    int tid = threadIdx.x;
    for (int s = 0; s < 2; ++s) {
        int p = tid + s*256;
        f4 v; v.x = 0.f; v.y = 0.f; v.z = 0.f; v.w = 0.f;
        if (p < 384) {
            int i = p >> 5, gk = p & 31, g = gk >> 3, k = gk & 7;
            int row = (g < 2) ? (2*J + g) : (128 + 2*J + (g - 2));
            int c0 = 16*k + 4*(i & 3);
            if (i < 8) {
                int tap = i >> 2;       // 0 = W0(prev), 1 = W1(res)
                const float* src = causal_w + ((size_t)(l*256 + row)*128 + c0)*2 + tap;
                v.x = src[0]; v.y = src[2]; v.z = src[4]; v.w = src[6];
            } else if (l >= 1) {        // F_{l-1}[row][c0..c0+3]
                float a0=0.f, a1=0.f, a2=0.f, a3=0.f;
                const float* w1 = causal_w + ((size_t)(l*256 + row)*128)*2 + 1;
                const float* rw = res_w + (size_t)(l-1)*128*128 + c0;
                for (int m2 = 0; m2 < 128; ++m2) {
                    float wv = w1[2*m2];
                    const float* rr = rw + (size_t)m2*128;
                    a0 += wv*rr[0]; a1 += wv*rr[1]; a2 += wv*rr[2]; a3 += wv*rr[3];
                }
                v.x = a0; v.y = a1; v.z = a2; v.w = a3;
            }
        } else {
            int q = p - 384, u = q >> 5, wk = q & 31, w = wk >> 3, k = wk & 7;
            int r = w & 1, isSkip = w >> 1;
            const float* mm = (isSkip ? skip_w : res_w)
                              + ((size_t)(l*128 + 2*J + r)*128 + 16*k + 4*u);
            v.x = mm[0]; v.y = mm[1]; v.z = mm[2]; v.w = mm[3];
        }
        chk[(size_t)(J*20 + l)*512 + p] = v;
    }
    if (tid < 4) {   // cb2 = causal_b + cond_b + W1_l·res_b[l-1]
        int row = (tid < 2) ? (2*J + tid) : (128 + 2*J + (tid - 2));
        float zb = 0.f;
        if (l >= 1) {
            const float* w1 = causal_w + ((size_t)(l*256 + row)*128)*2 + 1;
            for (int m2 = 0; m2 < 128; ++m2) zb += w1[2*m2]*res_b[(l-1)*128 + m2];
        }
        cb2[l*256 + row] = causal_b[l*256 + row] + cond_b[l*256 + row] + zb;
    }
}

// ============================================================
__global__ __launch_bounds__(NTHR, 1) void wn_gen(
    const float* __restrict__ enc,
    const float* __restrict__ first_w,  const float* __restrict__ first_b,
    const float* __restrict__ cond_w,
    const float* __restrict__ res_b,    const float* __restrict__ skip_b,
    const float* __restrict__ skipc_w,  const float* __restrict__ skipc_b,
    const float* __restrict__ fc_w,     const float* __restrict__ fc_b,
    const float* __restrict__ condf_w,  const float* __restrict__ condf_b,
    const float* __restrict__ logits_w, const float* __restrict__ logits_b,
    float* __restrict__ wsf, float* __restrict__ out)
{
    extern __shared__ float pool[];
    const int tid = threadIdx.x;
    const int J = blockIdx.x;
    float* ring = wsf + OFF_RING;
    f4* xb = (f4*)(wsf + OFF_X);
    const f4* chk = (const f4*)(wsf + OFF_CHK);
    const float* cb2 = wsf + OFF_CB2;
    int* wsl = (int*)(pool + P_WS);

    // ---------------- init: small LDS-resident weights ----------------
    if (tid < 256) {
        int r = tid >> 7, i = tid & 127;
        pool[P_WSKIPC + tid] = skipc_w[(size_t)(2*J + r)*128 + i];
        pool[P_WFC + tid]    = fc_w[(size_t)(2*J + r)*128 + i];
    }
    for (int m = tid; m < 512; m += NTHR) {
        int w = m >> 7, i = m & 127;
        pool[P_WLOG + m] = logits_w[(size_t)(4*J + w)*128 + i];
    }
    if (tid < 128) {
        pool[P_WF0 + tid] = first_w[2*tid];
        pool[P_WF1 + tid] = first_w[2*tid + 1];
        pool[P_FB + tid]  = first_b[tid];
    }
    if (tid < 40) {
        int l = tid >> 1, r = tid & 1;
        pool[P_RESB + tid]  = res_b[l*128 + 2*J + r];
        pool[P_SKIPB + tid] = skip_b[l*128 + 2*J + r];
    }
    if (tid < 4) pool[P_LOGB + tid] = logits_b[4*J + tid];
    if (tid < 2) pool[P_SKIPCB + tid] = skipc_b[2*J + tid];
    for (int m = tid; m < 2112; m += NTHR) pool[P_RES0 + m] = 0.f;
    if (tid < 8) { pool[P_XCUR + tid] = 128.f/255.f - 0.5f; pool[P_XPREV + tid] = 0.f; }
    __syncthreads();

    // weight prefetch thread-slot (shared by z and dres roles)
    const int zi = (tid >> 6)*8 + (tid & 7);

    // prime layer-0 weights
    f4 cw[16], nw[16];
    {
        const f4* cp = chk + (size_t)(J*20)*512;
        #pragma unroll
        for (int i = 0; i < 12; ++i) cw[i] = cp[i*32 + zi];
        #pragma unroll
        for (int u = 0; u < 4; ++u) cw[12+u] = cp[384 + u*32 + zi];
    }

    ull pfa = 0, pfb = 0;   // in-flight ring prefetch (lands next layer)
    float zpre = 0.f;       // W0_{l}·prev_l partial (computed previous layer)
    int e = 0, er_pending = 0;

    for (int t = 0; t < TT; ++t) {
        // ---- per-chunk precompute (c changes every 64 steps) ----
        if ((t & 63) == 0) {
            int te = t >> 6;
            for (int m = tid; m < 512; m += NTHR) {
                int b = m >> 6, j = m & 63;
                pool[P_CF + b*66 + j] = enc[(size_t)b*512 + j*8 + te];
            }
            __syncthreads();
            for (int m = tid; m < 640; m += NTHR) {
                int l = m >> 5, rem = m & 31, g = rem >> 3, b = rem & 7;
                int grow = (g < 2) ? (2*J + g) : (128 + 2*J + (g - 2));
                float acc = cb2[l*256 + grow];
                const float* cwp = cond_w + (size_t)(l*256 + grow)*64;
                const float* cf = pool + P_CF + b*66;
                for (int j = 0; j < 64; ++j) acc += cwp[j]*cf[j];
                pool[P_CONDZ + l*32 + g*8 + b] = acc;
            }
            if (tid < 16) {
                int r = tid >> 3, b = tid & 7, row = 2*J + r;
                float acc = fc_b[row] + condf_b[row];
                const float* cwp = condf_w + (size_t)row*64;
                const float* cf = pool + P_CF + b*66;
                for (int j = 0; j < 64; ++j) acc += cwp[j]*cf[j];
                pool[P_SFC + r*8 + b] = acc;
            }
            __syncthreads();
        }

        // ---- step start: ring slot counters, res_0, skip-init, R2 ----
        if (tid < 19) {
            int L = tid + 1, D = c_dil[L] + 2;
            int w = wsl[tid];
            wsl[tid] = (t == 0) ? 0 : ((w + 1 >= D) ? 0 : w + 1);
        }
        const int cur = t & 1;
        for (int m = tid; m < 1024; m += NTHR) {
            int b = m >> 7, r = m & 127;
            pool[P_RES0 + cur*1056 + b*132 + r] =
                pool[P_XPREV + b]*pool[P_WF0 + r] + pool[P_XCUR + b]*pool[P_WF1 + r] + pool[P_FB + r];
        }
        __syncthreads();
        {   // skip init (rows 2J..2J+1) + R2 init
            int w = tid >> 6, lane = tid & 63, b = lane >> 3, k = lane & 7;
            if (w < 2) {
                const float* wr = pool + P_WSKIPC + w*128 + 16*k;
                const float* rs = pool + P_RES0 + cur*1056 + b*132 + 16*k;
                float acc = 0.f;
                #pragma unroll
                for (int u = 0; u < 4; ++u)
                    acc += dot4(*(const f4*)(wr + 4*u), *(const f4*)(rs + 4*u));
                acc += __shfl_xor(acc,1); acc += __shfl_xor(acc,2); acc += __shfl_xor(acc,4);
                if (k == 0) pool[P_SKACC + w*8 + b] = acc + pool[P_SKIPCB + w];
            }
        }
        if (tid < 16) {
            int r = tid >> 3, b = tid & 7;
            pool[P_R2 + r*8 + b] = pool[P_RES0 + cur*1056 + b*132 + 2*J + r];
        }

        // ---- layer loop ----
        for (int l = 0; l < LL; ++l) {
            // A: land prev_{l+1} ring prefetch (issued last layer / head)
            if (l <= 18) {
                int b = tid >> 5, c = (tid & 31)*4;
                union { ull u; float f[2]; } u0, u1;
                u0.u = pfa; u1.u = pfb;
                float* dp = pool + P_PREVF + ((l+1)&1)*1056 + b*132 + c;
                dp[0] = u0.f[0]; dp[1] = u0.f[1]; dp[2] = u1.f[0]; dp[3] = u1.f[1];
            }
            // issue next-layer weights
            {
                int ln = (l + 1) % 20;
                const f4* cp = chk + (size_t)(J*20 + ln)*512;
                #pragma unroll
                for (int i = 0; i < 12; ++i) nw[i] = cp[i*32 + zi];
                #pragma unroll
                for (int u = 0; u < 4; ++u) nw[12+u] = cp[384 + u*32 + zi];
            }
            // issue ring prefetch for prev_{l+2}
            if (l <= 17) {
                int L = l + 2, d = c_dil[L];
                if (t >= d) {
                    int D = d + 2;
                    int rsl = wsl[L-1] + 2; if (rsl >= D) rsl -= D;
                    const float* rp = ring + c_roff2[L] + (size_t)rsl*1024 + tid*4;
                    pfa = __hip_atomic_load((const ull*)rp,     __ATOMIC_RELAXED, __HIP_MEMORY_SCOPE_AGENT);
                    pfb = __hip_atomic_load((const ull*)(rp+2), __ATOMIC_RELAXED, __HIP_MEMORY_SCOPE_AGENT);
                } else { pfa = 0; pfb = 0; }
            }
            // zrest: z_l = [zpre or W0·prev0] + W1·res_{l-1} + F_{l-1}·h_{l-1}
            {
                int g = tid >> 6, lane = tid & 63, b = lane >> 3, k = lane & 7;
                (void)g;
                const float* rs = ((l <= 1) ? pool + P_RES0 + cur*1056 : pool + P_RESF)
                                  + b*132 + 16*k;
                float acc;
                if (l == 0) {
                    const float* pv = pool + P_RES0 + (cur^1)*1056 + b*132 + 16*k;
                    acc = 0.f;
                    #pragma unroll
                    for (int u = 0; u < 4; ++u) acc += dot4(cw[u], *(const f4*)(pv + 4*u));
                } else acc = zpre;
                #pragma unroll
                for (int u = 0; u < 4; ++u) acc += dot4(cw[4+u], *(const f4*)(rs + 4*u));
                if (l >= 1) {
                    const float* hh = pool + P_HF + ((l-1)&1)*1056 + b*132 + 16*k;
                    #pragma unroll
                    for (int u = 0; u < 4; ++u) acc += dot4(cw[8+u], *(const f4*)(hh + 4*u));
                }
                acc += __shfl_xor(acc,1); acc += __shfl_xor(acc,2); acc += __shfl_xor(acc,4);
                if (k == 0) pool[P_SZ + (tid>>6)*8 + b] = acc;
            }
            __syncthreads();   // BAR1

            // B: wave0 computes h and publishes (wave-internal LDS ordering)
            ++e; int eh = e;
            if (tid < 64) {
                if (tid < 16) {
                    int r = tid & 1, b = tid >> 1;
                    float gg = pool[P_SZ + r*8 + b]     + pool[P_CONDZ + l*32 + r*8 + b];
                    float oo = pool[P_SZ + (2+r)*8 + b] + pool[P_CONDZ + l*32 + (2+r)*8 + b];
                    pool[P_SL + r*8 + b] = (1.f/(1.f + expf(-gg))) * tanhf(oo);
                }
                publish16(xb + (size_t)(eh & 3)*768, J, pool + P_SL, eh);
            }
            // zpre for layer l+1 (fills the publish->consume window)
            if (l <= 18) {
                int lane = tid & 63, b = lane >> 3, k = lane & 7;
                const float* pv = pool + P_PREVF + ((l+1)&1)*1056 + b*132 + 16*k;
                float z = 0.f;
                #pragma unroll
                for (int u = 0; u < 4; ++u) z += dot4(nw[u], *(const f4*)(pv + 4*u));
                zpre = z;
            }
            // C: consume h_l (+ res_{l-1} dual-polled, published a layer ago)
            if (l == 0 || l == 19)
                consume16(xb + (size_t)(eh & 3)*768, eh, pool + P_HF + (l&1)*1056, false);
            else
                consume_dual(xb + (size_t)(eh & 3)*768, eh, pool + P_HF + (l&1)*1056,
                             xb + (size_t)(er_pending & 3)*768, er_pending, pool + P_RESF);
            __syncthreads();   // BAR2

            // D: dres (waves 0,1) + skip accum (waves 2,3); ring store
            {
                int w = tid >> 6, lane = tid & 63, b = lane >> 3, k = lane & 7;
                int r = w & 1, isSkip = w >> 1;
                if (isSkip || l <= 18) {
                    const float* hh = pool + P_HF + (l&1)*1056 + b*132 + 16*k;
                    float acc = 0.f;
                    #pragma unroll
                    for (int u = 0; u < 4; ++u) acc += dot4(cw[12+u], *(const f4*)(hh + 4*u));
                    acc += __shfl_xor(acc,1); acc += __shfl_xor(acc,2); acc += __shfl_xor(acc,4);
                    if (k == 0) {
                        if (isSkip) {
                            pool[P_SKACC + r*8 + b] += acc + pool[P_SKIPB + l*2 + r];
                        } else {
                            float v = pool[P_R2 + r*8 + b] + acc + pool[P_RESB + l*2 + r];
                            pool[P_R2 + r*8 + b] = v;
                            pool[P_SL + r*8 + b] = v;
                            int ws2 = wsl[l];   // ring L = l+1 -> index l
                            float* wp = ring + c_roff2[l+1] + (size_t)ws2*1024 + b*128 + 2*J + r;
                            __hip_atomic_store(wp, v, __ATOMIC_RELAXED, __HIP_MEMORY_SCOPE_AGENT);
                        }
                    }
                }
            }
            __syncthreads();   // BAR3
            if (l <= 17) {     // publish res (consumed next layer, dual-polled)
                ++e;
                if (tid < 64) publish16(xb + (size_t)(e & 3)*768, J, pool + P_SL, e);
                er_pending = e;
            }
            // rotate weight buffers
            #pragma unroll
            for (int i = 0; i < 16; ++i) cw[i] = nw[i];
        }

        // ---- head ----
        // issue next step's prev_1 prefetch (lands at next step's layer 0)
        {
            int d = c_dil[1];
            if (t + 1 >= d) {
                int D = d + 2;
                int rsl = wsl[0] + 3; while (rsl >= D) rsl -= D;   // (w+1)+2 mod D
                const float* rp = ring + c_roff2[1] + (size_t)rsl*1024 + tid*4;
                pfa = __hip_atomic_load((const ull*)rp,     __ATOMIC_RELAXED, __HIP_MEMORY_SCOPE_AGENT);
                pfb = __hip_atomic_load((const ull*)(rp+2), __ATOMIC_RELAXED, __HIP_MEMORY_SCOPE_AGENT);
            } else { pfa = 0; pfb = 0; }
        }
        // skip exchange
        ++e;
        publish16(xb + (size_t)(e & 3)*768, J, pool + P_SKACC, e);
        consume16(xb + (size_t)(e & 3)*768, e, pool + P_HF, false);   // into HF[0]
        __syncthreads();
        // s rows 2J..2J+1 over relu(skip)
        {
            int w = tid >> 6, lane = tid & 63, b = lane >> 3, k = lane & 7;
            if (w < 2) {
                const float* wr = pool + P_WFC + w*128 + 16*k;
                const float* sk = pool + P_HF + b*132 + 16*k;
                float acc = 0.f;
                #pragma unroll
                for (int u = 0; u < 4; ++u) {
                    f4 sv = *(const f4*)(sk + 4*u);
                    sv.x = fmaxf(sv.x, 0.f); sv.y = fmaxf(sv.y, 0.f);
                    sv.z = fmaxf(sv.z, 0.f); sv.w = fmaxf(sv.w, 0.f);
                    acc += dot4(*(const f4*)(wr + 4*u), sv);
                }
                acc += __shfl_xor(acc,1); acc += __shfl_xor(acc,2); acc += __shfl_xor(acc,4);
                if (k == 0) pool[P_SL + w*8 + b] = acc + pool[P_SFC + w*8 + b];
            }
        }
        __syncthreads();
        ++e;
        publish16(xb + (size_t)(e & 3)*768, J, pool + P_SL, e);
        consume16(xb + (size_t)(e & 3)*768, e, pool + P_RESF, true);   // relu on scatter
        __syncthreads();
        // logits rows 4J..4J+3
        {
            int g = tid >> 6, lane = tid & 63, b = lane >> 3, k = lane & 7;
            const float* wr = pool + P_WLOG + g*128 + 16*k;
            const float* sv = pool + P_RESF + b*132 + 16*k;
            float acc = 0.f;
            #pragma unroll
            for (int u = 0; u < 4; ++u) acc += dot4(*(const f4*)(wr + 4*u), *(const f4*)(sv + 4*u));
            acc += __shfl_xor(acc,1); acc += __shfl_xor(acc,2); acc += __shfl_xor(acc,4);
            if (k == 0) {
                float v = acc + pool[P_LOGB + g];
                pool[P_SZ + g*8 + b] = v;
                out[4096 + ((size_t)(t*BB + b))*256 + 4*J + g] = v;
            }
        }
        __syncthreads();
        // local argmax over own 4 rows -> (val, idx) pair per batch
        if (tid < 8) {
            int b = tid;
            float best = -3.4e38f; int bi = 0;
            #pragma unroll
            for (int g = 0; g < 4; ++g) {
                float v = pool[P_SZ + g*8 + b];
                if (v > best) { best = v; bi = 4*J + g; }
            }
            pool[P_SL + b] = best;
            pool[P_SL + 8 + b] = (float)bi;
        }
        ++e;
        if (tid < 64) publish16(xb + (size_t)(e & 3)*768, J, pool + P_SL, e);
        consume16c(xb + (size_t)(e & 3)*768, e, pool + P_CAND);
        __syncthreads();
        // global argmax (replicated; first-index tie-break via min idx)
        {
            int b = tid >> 5, j = tid & 31;
            float v0 = pool[P_CAND + b*68 + j],       v1 = pool[P_CAND + b*68 + j + 32];
            int   i0 = (int)pool[P_CAND + 544 + b*68 + j];
            int   i1 = (int)pool[P_CAND + 544 + b*68 + j + 32];
            float bv; int bib;
            if (v1 > v0 || (v1 == v0 && i1 < i0)) { bv = v1; bib = i1; }
            else                                  { bv = v0; bib = i0; }
            #pragma unroll
            for (int m = 16; m >= 1; m >>= 1) {
                float ov = __shfl_xor(bv, m);
                int   oi = __shfl_xor(bib, m);
                if (ov > bv || (ov == bv && oi < bib)) { bv = ov; bib = oi; }
            }
            if (j == 0) {
                pool[P_XNEW + b] = (float)bib;
                if (J == 0) out[t*BB + b] = (float)bib;
            }
        }
        __syncthreads();
        if (tid < 8) {
            pool[P_XPREV + tid] = pool[P_XCUR + tid];
            pool[P_XCUR + tid]  = pool[P_XNEW + tid]*(1.f/255.f) - 0.5f;
        }
        __syncthreads();
    }
}

// ============================================================
extern "C" void kernel_launch(void* const* d_in, const int* in_sizes, int n_in,
                              void* d_out, int out_size, void* d_ws, size_t ws_size,
                              hipStream_t stream) {
    const float* enc      = (const float*)d_in[0];
    const float* first_w  = (const float*)d_in[1];
    const float* first_b  = (const float*)d_in[2];
    const float* causal_w = (const float*)d_in[3];
    const float* causal_b = (const float*)d_in[4];
    const float* cond_w   = (const float*)d_in[5];
    const float* cond_b   = (const float*)d_in[6];
    const float* res_w    = (const float*)d_in[7];
    const float* res_b    = (const float*)d_in[8];
    const float* skip_w   = (const float*)d_in[9];
    const float* skip_b   = (const float*)d_in[10];
    const float* skipc_w  = (const float*)d_in[11];
    const float* skipc_b  = (const float*)d_in[12];
    const float* fc_w     = (const float*)d_in[13];
    const float* fc_b     = (const float*)d_in[14];
    const float* condf_w  = (const float*)d_in[15];
    const float* condf_b  = (const float*)d_in[16];
    const float* logits_w = (const float*)d_in[17];
    const float* logits_b = (const float*)d_in[18];

    float* wsf = (float*)d_ws;
    float* out = (float*)d_out;

    wn_pack<<<NBLK*LL, NTHR, 0, stream>>>(causal_w, res_w, skip_w,
                                          causal_b, cond_b, res_b,
                                          (f4*)(wsf + OFF_CHK), wsf + OFF_CB2);
    wn_gen<<<NBLK, NTHR, 98304, stream>>>(
        enc, first_w, first_b, cond_w, res_b, skip_b, skipc_w, skipc_b,
        fc_w, fc_b, condf_w, condf_b, logits_w, logits_b, wsf, out);
}

// Round 8
// 38520.334 us; speedup vs baseline: 1.0229x; 1.0229x over previous
//
#include <hip/hip_runtime.h>
#include <math.h>

// ---------------- problem constants ----------------
#define BB 8
#define TT 512
#define LL 20
#define NBLK 64
#define NTHR 256

typedef float f4 __attribute__((ext_vector_type(4)));
typedef unsigned long long ull;

__constant__ int c_dil[LL] = {1,2,4,8,16,32,64,128,256,512,
                              1,2,4,8,16,32,64,128,256,512};
// ring float offsets, indexed by CONSUMING layer L (1..19); each ring has
// (d+2) slots of 1024 floats
__constant__ int c_roff2[LL] = {-1,0,4096,10240,20480,38912,73728,141312,274432,538624,
                                1064960,1068032,1072128,1078272,1088512,1106944,
                                1141760,1209344,1342464,1606656};

// ---------------- workspace layout (floats) ----------------
constexpr size_t OFF_RING = 0;          // 2,132,992 floats
constexpr size_t OFF_X    = 2132992;    // 4 slots * 768 f4 = 12,288 floats
constexpr size_t OFF_CHK  = 2145280;    // 64*20*576 f4 = 2,949,120 floats
constexpr size_t OFF_CB2  = 5094400;    // 20*256 folded z-bias
// end = 5,099,520 floats = 20.4 MB

// ---------------- LDS pool offsets (floats) ----------------
#define P_WSKIPC 0      // [2][128]
#define P_WLOG   512    // [4][128]
#define P_WF0    1024   // [128]
#define P_WF1    1152
#define P_FB     1280
#define P_CONDZ  1408   // [20][4][8]
#define P_RESB   2064   // [20][2]
#define P_SKIPB  2104
#define P_LOGB   2144   // [4]
#define P_SKIPCB 2148   // [2]
#define P_XCUR   2152   // [8]
#define P_XPREV  2160
#define P_XNEW   2168
#define P_SZ     2176   // [32]
#define P_SL     2208   // [32]
#define P_SKACC  2240   // [16]
#define P_R2     2256   // [16]
#define P_WS     2272   // [19] ints (ring write-slot counters)
#define P_CF     2292   // [8][66]
#define P_PREVF  2820   // [2][8][132] ping-pong
#define P_HF     4932   // [2][8][132] ping-pong
#define P_RESF   7044   // [8][132]
#define P_RES0   8100   // [2][8][132]
#define P_CAND   10212  // [2][8][68] argmax candidates (val, idx)
#define P_SFC2   11300  // [128][8] full s-bias (fc_b + condf_b + condf_w·c)
#define POOL_FL  12324
// dynamic LDS request padded to 96KB so only 1 block fits per CU

// ---------------- coherent 16B exchange primitives ----------
__device__ __forceinline__ f4 ldx(const f4* p) {
    f4 r;
    asm volatile("global_load_dwordx4 %0, %1, off sc0 sc1\n\ts_waitcnt vmcnt(0)"
                 : "=v"(r) : "v"(p) : "memory");
    return r;
}
__device__ __forceinline__ void ldx2(const f4* p0, const f4* p1, f4& a, f4& b) {
    asm volatile("global_load_dwordx4 %0, %2, off sc0 sc1\n\t"
                 "global_load_dwordx4 %1, %3, off sc0 sc1\n\t"
                 "s_waitcnt vmcnt(0)"
                 : "=v"(a), "=v"(b) : "v"(p0), "v"(p1) : "memory");
}
__device__ __forceinline__ void ldx4v(const f4* p0, const f4* p1, const f4* p2, const f4* p3,
                                      f4& a, f4& b, f4& c, f4& d) {
    asm volatile("global_load_dwordx4 %0, %4, off sc0 sc1\n\t"
                 "global_load_dwordx4 %1, %5, off sc0 sc1\n\t"
                 "global_load_dwordx4 %2, %6, off sc0 sc1\n\t"
                 "global_load_dwordx4 %3, %7, off sc0 sc1\n\t"
                 "s_waitcnt vmcnt(0)"
                 : "=v"(a),"=v"(b),"=v"(c),"=v"(d)
                 : "v"(p0),"v"(p1),"v"(p2),"v"(p3) : "memory");
}
__device__ __forceinline__ void stx_nd(f4* p, f4 v) {
    asm volatile("global_store_dwordx4 %0, %1, off sc0 sc1"
                 :: "v"(p), "v"(v) : "memory");
}

__device__ __forceinline__ float dot4(f4 a, f4 b) {
    return a.x*b.x + a.y*b.y + a.z*b.z + a.w*b.w;
}

// payload element E in [0,16): r=E>>3, b=E&7; vec = [3 payload | tag]
__device__ __forceinline__ void publish16(f4* slot, int J, const float* sl, int e) {
    if (threadIdx.x < 6) {
        int q = threadIdx.x;
        f4 v;
        v.x = sl[3*q];
        v.y = (3*q+1 < 16) ? sl[3*q+1] : 0.f;
        v.z = (3*q+2 < 16) ? sl[3*q+2] : 0.f;
        v.w = __int_as_float(e);
        stx_nd(slot + J*6 + q, v);
    }
}
__device__ __forceinline__ void scat16(float* dst, f4 v, int vi, bool dorelu) {
    int j = vi / 6, q = vi - 6*j;
    #pragma unroll
    for (int i = 0; i < 3; ++i) {
        int E = 3*q + i;
        if (E < 16) {
            float x = v[i];
            if (dorelu) x = fmaxf(x, 0.f);
            dst[(E & 7)*132 + 2*j + (E >> 3)] = x;
        }
    }
}
// PARALLEL RE-POLL: every round re-issues ALL lines with one vmcnt (r7 had
// serial per-vec spins: ~3 extra RTTs per consume -- the dominant cost)
__device__ __forceinline__ void consume16(const f4* slot, int e, float* dst, bool dorelu) {
    int m = threadIdx.x;
    const f4 *p0 = slot + m, *p1 = slot + 256 + m;
    f4 a, b;
    bool two = (m < 128);
    if (two) {
        ldx2(p0, p1, a, b);
        while (__float_as_int(a.w) != e || __float_as_int(b.w) != e) {
            __builtin_amdgcn_s_sleep(1);
            ldx2(p0, p1, a, b);
        }
    } else {
        a = ldx(p0);
        while (__float_as_int(a.w) != e) { __builtin_amdgcn_s_sleep(1); a = ldx(p0); }
    }
    scat16(dst, a, m, dorelu);
    if (two) scat16(dst, b, m + 256, dorelu);
}
__device__ __forceinline__ void consume_dual(const f4* sa, int ea, float* da,
                                             const f4* sb, int eb, float* db) {
    int m = threadIdx.x;
    const f4 *pa0 = sa + m, *pa1 = sa + 256 + m;
    const f4 *pb0 = sb + m, *pb1 = sb + 256 + m;
    f4 a0, a1, b0, b1;
    bool two = (m < 128);
    if (two) {
        ldx4v(pa0, pa1, pb0, pb1, a0, a1, b0, b1);
        while (__float_as_int(a0.w) != ea || __float_as_int(a1.w) != ea ||
               __float_as_int(b0.w) != eb || __float_as_int(b1.w) != eb) {
            __builtin_amdgcn_s_sleep(1);
            ldx4v(pa0, pa1, pb0, pb1, a0, a1, b0, b1);
        }
    } else {
        ldx2(pa0, pb0, a0, b0);
        while (__float_as_int(a0.w) != ea || __float_as_int(b0.w) != eb) {
            __builtin_amdgcn_s_sleep(1);
            ldx2(pa0, pb0, a0, b0);
        }
    }
    scat16(da, a0, m, false);
    scat16(db, b0, m, false);
    if (two) { scat16(da, a1, m + 256, false); scat16(db, b1, m + 256, false); }
}
// argmax-candidate consume: scatter (val,idx) pairs to cand[r][b][jb]
__device__ __forceinline__ void consume16c(const f4* slot, int e, float* dst) {
    int m = threadIdx.x;
    const f4 *p0 = slot + m, *p1 = slot + 256 + m;
    f4 a, b;
    bool two = (m < 128);
    if (two) {
        ldx2(p0, p1, a, b);
        while (__float_as_int(a.w) != e || __float_as_int(b.w) != e) {
            __builtin_amdgcn_s_sleep(1);
            ldx2(p0, p1, a, b);
        }
    } else {
        a = ldx(p0);
        while (__float_as_int(a.w) != e) { __builtin_amdgcn_s_sleep(1); a = ldx(p0); }
    }
    #pragma unroll
    for (int s = 0; s < 2; ++s) {
        if (s == 1 && !two) break;
        f4 v = s ? b : a;
        int vi = m + s*256;
        int jb = vi / 6, q = vi - 6*jb;
        #pragma unroll
        for (int i = 0; i < 3; ++i) {
            int E = 3*q + i;
            if (E < 16) dst[(E >> 3)*544 + (E & 7)*68 + jb] = v[i];
        }
    }
}

// ============================================================
// prep: pack per-block per-layer weight chunks.
// chunk (J,l): 576 f4.
//   z part      [i*32 + g*8 + k], i<12 (W0 i<4, W1 4..7, F 8..11), cols 16k+4(i&3)
//   dres part   [384 + u*32 + w*8 + k]  (legacy mapping; waves 2,3 = skip rows)
//   dres2 part  [512 + v*8 + low3]: res row r=low3>>2, cols 32*(low3&3)+4v
//               (wave0 computes BOTH res rows -> BAR3 eliminated)
// ============================================================
__global__ void wn_pack(const float* __restrict__ causal_w,
                        const float* __restrict__ res_w,
                        const float* __restrict__ skip_w,
                        const float* __restrict__ causal_b,
                        const float* __restrict__ cond_b,
                        const float* __restrict__ res_b,
                        f4* __restrict__ chk, float* __restrict__ cb2)
{
    int bx = blockIdx.x;
    int J = bx / 20, l = bx - J*20;
    int tid = threadIdx.x;
    for (int s = 0; s < 3; ++s) {
        int p = tid + s*256;
        if (p >= 576) break;
        f4 v; v.x = 0.f; v.y = 0.f; v.z = 0.f; v.w = 0.f;
        if (p < 384) {
            int i = p >> 5, gk = p & 31, g = gk >> 3, k = gk & 7;
            int row = (g < 2) ? (2*J + g) : (128 + 2*J + (g - 2));
            int c0 = 16*k + 4*(i & 3);
            if (i < 8) {
                int tap = i >> 2;       // 0 = W0(prev), 1 = W1(res)
                const float* src = causal_w + ((size_t)(l*256 + row)*128 + c0)*2 + tap;
                v.x = src[0]; v.y = src[2]; v.z = src[4]; v.w = src[6];
            } else if (l >= 1) {        // F_{l-1}[row][c0..c0+3]
                float a0=0.f, a1=0.f, a2=0.f, a3=0.f;
                const float* w1 = causal_w + ((size_t)(l*256 + row)*128)*2 + 1;
                const float* rw = res_w + (size_t)(l-1)*128*128 + c0;
                for (int m2 = 0; m2 < 128; ++m2) {
                    float wv = w1[2*m2];
                    const float* rr = rw + (size_t)m2*128;
                    a0 += wv*rr[0]; a1 += wv*rr[1]; a2 += wv*rr[2]; a3 += wv*rr[3];
                }
                v.x = a0; v.y = a1; v.z = a2; v.w = a3;
            }
        } else if (p < 512) {
            int q = p - 384, u = q >> 5, wk = q & 31, w = wk >> 3, k = wk & 7;
            int r = w & 1, isSkip = w >> 1;
            const float* mm = (isSkip ? skip_w : res_w)
                              + ((size_t)(l*128 + 2*J + r)*128 + 16*k + 4*u);
            v.x = mm[0]; v.y = mm[1]; v.z = mm[2]; v.w = mm[3];
        } else {
            int q = p - 512, vv = q >> 3, low3 = q & 7;
            int r = low3 >> 2, k2 = low3 & 3;
            const float* mm = res_w + ((size_t)(l*128 + 2*J + r)*128 + 32*k2 + 4*vv);
            v.x = mm[0]; v.y = mm[1]; v.z = mm[2]; v.w = mm[3];
        }
        chk[(size_t)(J*20 + l)*576 + p] = v;
    }
    if (tid < 4) {   // cb2 = causal_b + cond_b + W1_l·res_b[l-1]
        int row = (tid < 2) ? (2*J + tid) : (128 + 2*J + (tid - 2));
        float zb = 0.f;
        if (l >= 1) {
            const float* w1 = causal_w + ((size_t)(l*256 + row)*128)*2 + 1;
            for (int m2 = 0; m2 < 128; ++m2) zb += w1[2*m2]*res_b[(l-1)*128 + m2];
        }
        cb2[l*256 + row] = causal_b[l*256 + row] + cond_b[l*256 + row] + zb;
    }
}

// ============================================================
__global__ __launch_bounds__(NTHR, 1) void wn_gen(
    const float* __restrict__ enc,
    const float* __restrict__ first_w,  const float* __restrict__ first_b,
    const float* __restrict__ cond_w,
    const float* __restrict__ res_b,    const float* __restrict__ skip_b,
    const float* __restrict__ skipc_w,  const float* __restrict__ skipc_b,
    const float* __restrict__ fc_w,     const float* __restrict__ fc_b,
    const float* __restrict__ condf_w,  const float* __restrict__ condf_b,
    const float* __restrict__ logits_w, const float* __restrict__ logits_b,
    float* __restrict__ wsf, float* __restrict__ out)
{
    extern __shared__ float pool[];
    const int tid = threadIdx.x;
    const int J = blockIdx.x;
    float* ring = wsf + OFF_RING;
    f4* xb = (f4*)(wsf + OFF_X);
    const f4* chk = (const f4*)(wsf + OFF_CHK);
    const float* cb2 = wsf + OFF_CB2;
    int* wsl = (int*)(pool + P_WS);

    // ---------------- init ----------------
    if (tid < 256) {
        int r = tid >> 7, i = tid & 127;
        pool[P_WSKIPC + tid] = skipc_w[(size_t)(2*J + r)*128 + i];
    }
    for (int m = tid; m < 512; m += NTHR) {
        int w = m >> 7, i = m & 127;
        pool[P_WLOG + m] = logits_w[(size_t)(4*J + w)*128 + i];
    }
    if (tid < 128) {
        pool[P_WF0 + tid] = first_w[2*tid];
        pool[P_WF1 + tid] = first_w[2*tid + 1];
        pool[P_FB + tid]  = first_b[tid];
    }
    if (tid < 40) {
        int l = tid >> 1, r = tid & 1;
        pool[P_RESB + tid]  = res_b[l*128 + 2*J + r];
        pool[P_SKIPB + tid] = skip_b[l*128 + 2*J + r];
    }
    if (tid < 4) pool[P_LOGB + tid] = logits_b[4*J + tid];
    if (tid < 2) pool[P_SKIPCB + tid] = skipc_b[2*J + tid];
    for (int m = tid; m < 2112; m += NTHR) pool[P_RES0 + m] = 0.f;
    if (tid < 8) { pool[P_XCUR + tid] = 128.f/255.f - 0.5f; pool[P_XPREV + tid] = 0.f; }
    __syncthreads();

    const int zi = (tid >> 6)*8 + (tid & 7);
    const int low3 = (tid & 63) & 7;

    // head fc weights: thread (og=tid>>3, k=tid&7) handles s-rows og*4..og*4+3,
    // cols 16k..16k+15
    f4 fcw2[16];
    {
        int og = tid >> 3, k = tid & 7;
        #pragma unroll
        for (int oi = 0; oi < 4; ++oi)
            #pragma unroll
            for (int u = 0; u < 4; ++u)
                fcw2[oi*4+u] = *(const f4*)(fc_w + (size_t)(og*4+oi)*128 + 16*k + 4*u);
    }

    // prime layer-0 weights
    f4 cw[16], nw[16], cw2[8], nw2[8];
    {
        const f4* cp = chk + (size_t)(J*20)*576;
        #pragma unroll
        for (int i = 0; i < 12; ++i) cw[i] = cp[i*32 + zi];
        #pragma unroll
        for (int u = 0; u < 4; ++u) cw[12+u] = cp[384 + u*32 + zi];
        #pragma unroll
        for (int v = 0; v < 8; ++v) cw2[v] = cp[512 + v*8 + low3];
    }

    ull pfa = 0, pfb = 0;
    float zpre = 0.f;
    int e = 0, er_pending = 0;

    for (int t = 0; t < TT; ++t) {
        // ---- per-chunk precompute (c changes every 64 steps) ----
        if ((t & 63) == 0) {
            int te = t >> 6;
            for (int m = tid; m < 512; m += NTHR) {
                int b = m >> 6, j = m & 63;
                pool[P_CF + b*66 + j] = enc[(size_t)b*512 + j*8 + te];
            }
            __syncthreads();
            for (int m = tid; m < 640; m += NTHR) {
                int l = m >> 5, rem = m & 31, g = rem >> 3, b = rem & 7;
                int grow = (g < 2) ? (2*J + g) : (128 + 2*J + (g - 2));
                float acc = cb2[l*256 + grow];
                const float* cwp = cond_w + (size_t)(l*256 + grow)*64;
                const float* cf = pool + P_CF + b*66;
                for (int j = 0; j < 64; ++j) acc += cwp[j]*cf[j];
                pool[P_CONDZ + l*32 + g*8 + b] = acc;
            }
            for (int m = tid; m < 1024; m += NTHR) {   // full sfc[o][b]
                int o = m >> 3, b = m & 7;
                float acc = fc_b[o] + condf_b[o];
                const float* cwp = condf_w + (size_t)o*64;
                const float* cf = pool + P_CF + b*66;
                for (int j = 0; j < 64; ++j) acc += cwp[j]*cf[j];
                pool[P_SFC2 + m] = acc;
            }
            __syncthreads();
        }

        // ---- step start ----
        if (tid < 19) {
            int L = tid + 1, D = c_dil[L] + 2;
            int w = wsl[tid];
            wsl[tid] = (t == 0) ? 0 : ((w + 1 >= D) ? 0 : w + 1);
        }
        const int cur = t & 1;
        for (int m = tid; m < 1024; m += NTHR) {
            int b = m >> 7, r = m & 127;
            pool[P_RES0 + cur*1056 + b*132 + r] =
                pool[P_XPREV + b]*pool[P_WF0 + r] + pool[P_XCUR + b]*pool[P_WF1 + r] + pool[P_FB + r];
        }
        __syncthreads();
        {   // skip init (rows 2J..2J+1)
            int w = tid >> 6, lane = tid & 63, b = lane >> 3, k = lane & 7;
            if (w < 2) {
                const float* wr = pool + P_WSKIPC + w*128 + 16*k;
                const float* rs = pool + P_RES0 + cur*1056 + b*132 + 16*k;
                float acc = 0.f;
                #pragma unroll
                for (int u = 0; u < 4; ++u)
                    acc += dot4(*(const f4*)(wr + 4*u), *(const f4*)(rs + 4*u));
                acc += __shfl_xor(acc,1); acc += __shfl_xor(acc,2); acc += __shfl_xor(acc,4);
                if (k == 0) pool[P_SKACC + w*8 + b] = acc + pool[P_SKIPCB + w];
            }
        }
        if (tid < 16) {
            int r = tid >> 3, b = tid & 7;
            pool[P_R2 + r*8 + b] = pool[P_RES0 + cur*1056 + b*132 + 2*J + r];
        }

        // ---- layer loop ----
        for (int l = 0; l < LL; ++l) {
            // A: land prev_{l+1} ring prefetch
            if (l <= 18) {
                int b = tid >> 5, c = (tid & 31)*4;
                union { ull u; float f[2]; } u0, u1;
                u0.u = pfa; u1.u = pfb;
                float* dp = pool + P_PREVF + ((l+1)&1)*1056 + b*132 + c;
                dp[0] = u0.f[0]; dp[1] = u0.f[1]; dp[2] = u1.f[0]; dp[3] = u1.f[1];
            }
            // issue next-layer weights
            {
                int ln = (l + 1) % 20;
                const f4* cp = chk + (size_t)(J*20 + ln)*576;
                #pragma unroll
                for (int i = 0; i < 12; ++i) nw[i] = cp[i*32 + zi];
                #pragma unroll
                for (int u = 0; u < 4; ++u) nw[12+u] = cp[384 + u*32 + zi];
                #pragma unroll
                for (int v = 0; v < 8; ++v) nw2[v] = cp[512 + v*8 + low3];
            }
            // issue ring prefetch for prev_{l+2}
            if (l <= 17) {
                int L = l + 2, d = c_dil[L];
                if (t >= d) {
                    int D = d + 2;
                    int rsl = wsl[L-1] + 2; if (rsl >= D) rsl -= D;
                    const float* rp = ring + c_roff2[L] + (size_t)rsl*1024 + tid*4;
                    pfa = __hip_atomic_load((const ull*)rp,     __ATOMIC_RELAXED, __HIP_MEMORY_SCOPE_AGENT);
                    pfb = __hip_atomic_load((const ull*)(rp+2), __ATOMIC_RELAXED, __HIP_MEMORY_SCOPE_AGENT);
                } else { pfa = 0; pfb = 0; }
            }
            // zrest
            {
                int lane = tid & 63, b = lane >> 3, k = lane & 7;
                const float* rs = ((l <= 1) ? pool + P_RES0 + cur*1056 : pool + P_RESF)
                                  + b*132 + 16*k;
                float acc;
                if (l == 0) {
                    const float* pv = pool + P_RES0 + (cur^1)*1056 + b*132 + 16*k;
                    acc = 0.f;
                    #pragma unroll
                    for (int u = 0; u < 4; ++u) acc += dot4(cw[u], *(const f4*)(pv + 4*u));
                } else acc = zpre;
                #pragma unroll
                for (int u = 0; u < 4; ++u) acc += dot4(cw[4+u], *(const f4*)(rs + 4*u));
                if (l >= 1) {
                    const float* hh = pool + P_HF + ((l-1)&1)*1056 + b*132 + 16*k;
                    #pragma unroll
                    for (int u = 0; u < 4; ++u) acc += dot4(cw[8+u], *(const f4*)(hh + 4*u));
                }
                acc += __shfl_xor(acc,1); acc += __shfl_xor(acc,2); acc += __shfl_xor(acc,4);
                if (k == 0) pool[P_SZ + (tid>>6)*8 + b] = acc;
            }
            __syncthreads();   // BAR1

            // wave0: h + publish
            ++e; int eh = e;
            if (tid < 64) {
                if (tid < 16) {
                    int r = tid & 1, b = tid >> 1;
                    float gg = pool[P_SZ + r*8 + b]     + pool[P_CONDZ + l*32 + r*8 + b];
                    float oo = pool[P_SZ + (2+r)*8 + b] + pool[P_CONDZ + l*32 + (2+r)*8 + b];
                    pool[P_SL + r*8 + b] = (1.f/(1.f + expf(-gg))) * tanhf(oo);
                }
                publish16(xb + (size_t)(eh & 3)*768, J, pool + P_SL, eh);
            }
            // zpre for l+1 (fills the publish->consume window)
            if (l <= 18) {
                int lane = tid & 63, b = lane >> 3, k = lane & 7;
                const float* pv = pool + P_PREVF + ((l+1)&1)*1056 + b*132 + 16*k;
                float z = 0.f;
                #pragma unroll
                for (int u = 0; u < 4; ++u) z += dot4(nw[u], *(const f4*)(pv + 4*u));
                zpre = z;
            }
            // consume h_l (+ res_{l-1}, published a layer ago)
            if (l == 0 || l == 19)
                consume16(xb + (size_t)(eh & 3)*768, eh, pool + P_HF + (l&1)*1056, false);
            else
                consume_dual(xb + (size_t)(eh & 3)*768, eh, pool + P_HF + (l&1)*1056,
                             xb + (size_t)(er_pending & 3)*768, er_pending, pool + P_RESF);
            __syncthreads();   // BAR2

            // D: wave0 = BOTH res rows (cw2) + ring store; waves 2,3 = skip
            {
                int w = tid >> 6;
                if (w == 0) {
                    if (l <= 18) {
                        int lane = tid & 63, b = lane >> 3;
                        int r = low3 >> 2, k2 = low3 & 3;
                        const float* hh = pool + P_HF + (l&1)*1056 + b*132 + 32*k2;
                        float acc = 0.f;
                        #pragma unroll
                        for (int v = 0; v < 8; ++v) acc += dot4(cw2[v], *(const f4*)(hh + 4*v));
                        acc += __shfl_xor(acc,1); acc += __shfl_xor(acc,2);
                        if (k2 == 0) {
                            float vv = pool[P_R2 + r*8 + b] + acc + pool[P_RESB + l*2 + r];
                            pool[P_R2 + r*8 + b] = vv;
                            pool[P_SL + r*8 + b] = vv;
                            int ws2 = wsl[l];
                            float* wp = ring + c_roff2[l+1] + (size_t)ws2*1024 + b*128 + 2*J + r;
                            __hip_atomic_store(wp, vv, __ATOMIC_RELAXED, __HIP_MEMORY_SCOPE_AGENT);
                        }
                    }
                } else if (w >= 2) {
                    int lane = tid & 63, b = lane >> 3, k = lane & 7;
                    int r = w & 1;
                    const float* hh = pool + P_HF + (l&1)*1056 + b*132 + 16*k;
                    float acc = 0.f;
                    #pragma unroll
                    for (int u = 0; u < 4; ++u) acc += dot4(cw[12+u], *(const f4*)(hh + 4*u));
                    acc += __shfl_xor(acc,1); acc += __shfl_xor(acc,2); acc += __shfl_xor(acc,4);
                    if (k == 0) pool[P_SKACC + r*8 + b] += acc + pool[P_SKIPB + l*2 + r];
                }
            }
            // publish res (wave0 program order guarantees its D is done; no BAR3)
            if (l <= 17) {
                ++e;
                publish16(xb + (size_t)(e & 3)*768, J, pool + P_SL, e);
                er_pending = e;
            }
            // rotate
            #pragma unroll
            for (int i = 0; i < 16; ++i) cw[i] = nw[i];
            #pragma unroll
            for (int v = 0; v < 8; ++v) cw2[v] = nw2[v];
        }

        // ---- head ----
        __syncthreads();   // P_SKACC (waves 2,3) -> wave0 publish
        // issue next step's prev_1 prefetch
        {
            int d = c_dil[1];
            if (t + 1 >= d) {
                int D = d + 2;
                int rsl = wsl[0] + 3; while (rsl >= D) rsl -= D;
                const float* rp = ring + c_roff2[1] + (size_t)rsl*1024 + tid*4;
                pfa = __hip_atomic_load((const ull*)rp,     __ATOMIC_RELAXED, __HIP_MEMORY_SCOPE_AGENT);
                pfb = __hip_atomic_load((const ull*)(rp+2), __ATOMIC_RELAXED, __HIP_MEMORY_SCOPE_AGENT);
            } else { pfa = 0; pfb = 0; }
        }
        // skip exchange (relu applied on scatter)
        ++e;
        publish16(xb + (size_t)(e & 3)*768, J, pool + P_SKACC, e);
        consume16(xb + (size_t)(e & 3)*768, e, pool + P_HF, true);
        __syncthreads();
        // local FULL s: s[b][o] = relu_skip[b]·fc_w[o] + sfc2[o][b]; relu -> P_RESF
        {
            int og = tid >> 3, k = tid & 7;
            float accs[32];
            #pragma unroll
            for (int b = 0; b < 8; ++b) {
                const float* hh = pool + P_HF + b*132 + 16*k;
                f4 h0 = *(const f4*)(hh),     h1 = *(const f4*)(hh + 4);
                f4 h2 = *(const f4*)(hh + 8), h3 = *(const f4*)(hh + 12);
                #pragma unroll
                for (int oi = 0; oi < 4; ++oi)
                    accs[oi*8+b] = dot4(fcw2[oi*4+0], h0) + dot4(fcw2[oi*4+1], h1)
                                 + dot4(fcw2[oi*4+2], h2) + dot4(fcw2[oi*4+3], h3);
            }
            #pragma unroll
            for (int i = 0; i < 32; ++i) {
                accs[i] += __shfl_xor(accs[i], 1);
                accs[i] += __shfl_xor(accs[i], 2);
                accs[i] += __shfl_xor(accs[i], 4);
            }
            if (k == 0) {
                #pragma unroll
                for (int oi = 0; oi < 4; ++oi) {
                    int o = og*4 + oi;
                    #pragma unroll
                    for (int b = 0; b < 8; ++b)
                        pool[P_RESF + b*132 + o] =
                            fmaxf(accs[oi*8+b] + pool[P_SFC2 + o*8 + b], 0.f);
                }
            }
        }
        __syncthreads();
        // logits rows 4J..4J+3
        {
            int g = tid >> 6, lane = tid & 63, b = lane >> 3, k = lane & 7;
            const float* wr = pool + P_WLOG + g*128 + 16*k;
            const float* sv = pool + P_RESF + b*132 + 16*k;
            float acc = 0.f;
            #pragma unroll
            for (int u = 0; u < 4; ++u) acc += dot4(*(const f4*)(wr + 4*u), *(const f4*)(sv + 4*u));
            acc += __shfl_xor(acc,1); acc += __shfl_xor(acc,2); acc += __shfl_xor(acc,4);
            if (k == 0) {
                float v = acc + pool[P_LOGB + g];
                pool[P_SZ + g*8 + b] = v;
                out[4096 + ((size_t)(t*BB + b))*256 + 4*J + g] = v;
            }
        }
        __syncthreads();
        // local argmax over own 4 rows -> (val, idx)
        if (tid < 8) {
            int b = tid;
            float best = -3.4e38f; int bi = 0;
            #pragma unroll
            for (int g = 0; g < 4; ++g) {
                float v = pool[P_SZ + g*8 + b];
                if (v > best) { best = v; bi = 4*J + g; }
            }
            pool[P_SL + b] = best;
            pool[P_SL + 8 + b] = (float)bi;
        }
        ++e;
        if (tid < 64) publish16(xb + (size_t)(e & 3)*768, J, pool + P_SL, e);
        consume16c(xb + (size_t)(e & 3)*768, e, pool + P_CAND);
        __syncthreads();
        // global argmax (replicated; first-index tie-break)
        {
            int b = tid >> 5, j = tid & 31;
            float v0 = pool[P_CAND + b*68 + j],       v1 = pool[P_CAND + b*68 + j + 32];
            int   i0 = (int)pool[P_CAND + 544 + b*68 + j];
            int   i1 = (int)pool[P_CAND + 544 + b*68 + j + 32];
            float bv; int bib;
            if (v1 > v0 || (v1 == v0 && i1 < i0)) { bv = v1; bib = i1; }
            else                                  { bv = v0; bib = i0; }
            #pragma unroll
            for (int m = 16; m >= 1; m >>= 1) {
                float ov = __shfl_xor(bv, m);
                int   oi = __shfl_xor(bib, m);
                if (ov > bv || (ov == bv && oi < bib)) { bv = ov; bib = oi; }
            }
            if (j == 0) {
                pool[P_XNEW + b] = (float)bib;
                if (J == 0) out[t*BB + b] = (float)bib;
            }
        }
        __syncthreads();
        if (tid < 8) {
            pool[P_XPREV + tid] = pool[P_XCUR + tid];
            pool[P_XCUR + tid]  = pool[P_XNEW + tid]*(1.f/255.f) - 0.5f;
        }
        __syncthreads();
    }
}

// ============================================================
extern "C" void kernel_launch(void* const* d_in, const int* in_sizes, int n_in,
                              void* d_out, int out_size, void* d_ws, size_t ws_size,
                              hipStream_t stream) {
    const float* enc      = (const float*)d_in[0];
    const float* first_w  = (const float*)d_in[1];
    const float* first_b  = (const float*)d_in[2];
    const float* causal_w = (const float*)d_in[3];
    const float* causal_b = (const float*)d_in[4];
    const float* cond_w   = (const float*)d_in[5];
    const float* cond_b   = (const float*)d_in[6];
    const float* res_w    = (const float*)d_in[7];
    const float* res_b    = (const float*)d_in[8];
    const float* skip_w   = (const float*)d_in[9];
    const float* skip_b   = (const float*)d_in[10];
    const float* skipc_w  = (const float*)d_in[11];
    const float* skipc_b  = (const float*)d_in[12];
    const float* fc_w     = (const float*)d_in[13];
    const float* fc_b     = (const float*)d_in[14];
    const float* condf_w  = (const float*)d_in[15];
    const float* condf_b  = (const float*)d_in[16];
    const float* logits_w = (const float*)d_in[17];
    const float* logits_b = (const float*)d_in[18];

    float* wsf = (float*)d_ws;
    float* out = (float*)d_out;

    wn_pack<<<NBLK*LL, NTHR, 0, stream>>>(causal_w, res_w, skip_w,
                                          causal_b, cond_b, res_b,
                                          (f4*)(wsf + OFF_CHK), wsf + OFF_CB2);
    wn_gen<<<NBLK, NTHR, 98304, stream>>>(
        enc, first_w, first_b, cond_w, res_b, skip_b, skipc_w, skipc_b,
        fc_w, fc_b, condf_w, condf_b, logits_w, logits_b, wsf, out);
}